// Round 1
// baseline (1458.217 us; speedup 1.0000x reference)
//
#include <hip/hip_runtime.h>
#include <hip/hip_bf16.h>
#include <math.h>

#define CIN 128
#define HH 128
#define WW 128
#define HWX (HH*WW)
#define COUT 256
#define KK 9
#define NB 4

// ---------------------------------------------------------------------------
// Kernel A: offset/mask conv (27ch, 3x3, pad 1) + sampling-table epilogue.
// Tile: 32(x) x 16(y) pixels, 256 threads, 2 pixels (x-pair) per thread.
// Outputs per (b, kk, pix): packed clamped corners (u32) + float4 corner
// weights with mask and validity folded in.
// ---------------------------------------------------------------------------
__global__ __launch_bounds__(256) void offmask_kernel(
    const float* __restrict__ x, const float* __restrict__ offw,
    const float* __restrict__ offb, const float* __restrict__ modw,
    const float* __restrict__ modb,
    unsigned int* __restrict__ pk_out, float4* __restrict__ w4_out)
{
    __shared__ float xs[8][18][34];   // c, y, x (halo 1 each side)
    __shared__ float wsm[8][9][27];   // c, tap, out-channel

    const int tid = threadIdx.x;
    const int tx = tid & 15;          // 0..15 -> pixel pair 2*tx, 2*tx+1
    const int ty = tid >> 4;          // 0..15
    const int b   = blockIdx.z;
    const int ty0 = blockIdx.y * 16;
    const int tx0 = blockIdx.x * 32;

    float acc[27][2];
#pragma unroll
    for (int o = 0; o < 27; ++o) { acc[o][0] = 0.f; acc[o][1] = 0.f; }

    for (int c0 = 0; c0 < CIN; c0 += 8) {
        // stage x tile
        for (int e = tid; e < 8 * 18 * 34; e += 256) {
            int c = e / 612;
            int rem = e - c * 612;
            int r = rem / 34;
            int col = rem - r * 34;
            int gy = ty0 + r - 1, gx = tx0 + col - 1;
            float v = 0.f;
            if (gy >= 0 && gy < HH && gx >= 0 && gx < WW)
                v = x[(((b * CIN) + (c0 + c)) << 14) + (gy << 7) + gx];
            xs[c][r][col] = v;
        }
        // stage weights for these 8 channels (18 offset ch + 9 mod ch)
        for (int e = tid; e < 8 * 9 * 27; e += 256) {
            int o = e % 27;
            int t = (e / 27) % 9;
            int c = e / 243;
            float v;
            if (o < 18) v = offw[((o * CIN) + (c0 + c)) * 9 + t];
            else        v = modw[(((o - 18) * CIN) + (c0 + c)) * 9 + t];
            wsm[c][t][o] = v;
        }
        __syncthreads();

#pragma unroll 1
        for (int c = 0; c < 8; ++c) {
            float xr[3][4];
#pragma unroll
            for (int dy = 0; dy < 3; ++dy)
#pragma unroll
                for (int dx = 0; dx < 4; ++dx)
                    xr[dy][dx] = xs[c][ty + dy][(tx << 1) + dx];
#pragma unroll
            for (int t = 0; t < 9; ++t) {
                const int dy = t / 3, dx = t % 3;
                float v0 = xr[dy][dx];
                float v1 = xr[dy][dx + 1];
#pragma unroll
                for (int o = 0; o < 27; ++o) {
                    float w = wsm[c][t][o];
                    acc[o][0] = fmaf(v0, w, acc[o][0]);
                    acc[o][1] = fmaf(v1, w, acc[o][1]);
                }
            }
        }
        __syncthreads();
    }

    // epilogue: build sampling tables
    const int ho = ty0 + ty;
#pragma unroll
    for (int j = 0; j < 2; ++j) {
        const int wo = tx0 + (tx << 1) + j;
        const int pix = (ho << 7) + wo;
#pragma unroll
        for (int kk = 0; kk < 9; ++kk) {
            float oy = acc[2 * kk][j] + offb[2 * kk];
            float ox = acc[2 * kk + 1][j] + offb[2 * kk + 1];
            float mt = acc[18 + kk][j] + modb[kk];
            float m = 2.f / (1.f + expf(-mt));
            float py = (float)(ho - 1 + kk / 3) + oy;
            float px = (float)(wo - 1 + kk % 3) + ox;
            float y0f = floorf(py), x0f = floorf(px);
            float wy = py - y0f, wx = px - x0f;
            int y0 = (int)y0f, x0 = (int)x0f;
            int y1 = y0 + 1, x1 = x0 + 1;
            float vy0 = (y0 >= 0 && y0 < HH) ? 1.f : 0.f;
            float vy1 = (y1 >= 0 && y1 < HH) ? 1.f : 0.f;
            float vx0 = (x0 >= 0 && x0 < WW) ? 1.f : 0.f;
            float vx1 = (x1 >= 0 && x1 < WW) ? 1.f : 0.f;
            float a  = m * (1.f - wy) * vy0;
            float bb = m * wy * vy1;
            float u  = (1.f - wx) * vx0;
            float vv = wx * vx1;
            int y0c = min(max(y0, 0), HH - 1), y1c = min(max(y1, 0), HH - 1);
            int x0c = min(max(x0, 0), WW - 1), x1c = min(max(x1, 0), WW - 1);
            unsigned int pk = (unsigned)y0c | ((unsigned)x0c << 7) |
                              ((unsigned)y1c << 14) | ((unsigned)x1c << 21);
            int oidx = ((b * 9 + kk) << 14) + pix;
            pk_out[oidx] = pk;
            w4_out[oidx] = make_float4(a * u, a * vv, bb * u, bb * vv);
        }
    }
}

// ---------------------------------------------------------------------------
// Kernel C: weight transpose  wt[kk][c][o] = w[o][c][kk]
// ---------------------------------------------------------------------------
__global__ __launch_bounds__(256) void wtrans_kernel(
    const float* __restrict__ w, float* __restrict__ wt)
{
    int i = blockIdx.x * 256 + threadIdx.x;   // over 256*128*9 = 294912
    int o = i / (CIN * 9);
    int r = i - o * (CIN * 9);
    int c = r / 9;
    int kk = r - c * 9;
    wt[(kk * CIN + c) * COUT + o] = w[i];
}

// ---------------------------------------------------------------------------
// Kernel B: deformable GEMM.  out[b][o][pix] = sum_{c,kk} samp * wt
// Block tile: 64 cout x 64 pixels, K-chunks of 16 channels per kk.
// samp tile built on the fly from 4 gathers/value (channel-invariant corners).
// ---------------------------------------------------------------------------
__global__ __launch_bounds__(256) void dgemm_kernel(
    const float* __restrict__ x, const float* __restrict__ wtp,
    const unsigned int* __restrict__ pk, const float4* __restrict__ w4,
    float* __restrict__ out)
{
    __shared__ float samp_s[16][64];
    __shared__ float wt_s[16][64];
    __shared__ unsigned int pk_s[64];
    __shared__ float4 w4_s[64];

    const int tid = threadIdx.x;
    const int tx = tid & 15;     // pixel group (4 px each)
    const int ty = tid >> 4;     // cout group (4 each)
    const int pix0 = blockIdx.x * 64;
    const int o0   = blockIdx.y * 64;
    const int b    = blockIdx.z;
    const float* xb = x + ((size_t)(b * CIN) << 14);

    float acc[4][4];
#pragma unroll
    for (int i = 0; i < 4; ++i)
#pragma unroll
        for (int j = 0; j < 4; ++j) acc[i][j] = 0.f;

    for (int kk = 0; kk < 9; ++kk) {
        if (tid < 64) {
            int gi = ((b * 9 + kk) << 14) + pix0 + tid;
            pk_s[tid] = pk[gi];
            w4_s[tid] = w4[gi];
        }
        __syncthreads();

        for (int c0 = 0; c0 < CIN; c0 += 16) {
            // build samp tile (16 ch x 64 px) + weight tile (16 ch x 64 cout)
#pragma unroll
            for (int e0 = 0; e0 < 4; ++e0) {
                int e = tid + (e0 << 8);
                int c = e >> 6, p = e & 63;
                unsigned int k_ = pk_s[p];
                float4 w = w4_s[p];
                const float* xc = xb + ((c0 + c) << 14);
                int y0 = k_ & 127, xx0 = (k_ >> 7) & 127;
                int y1 = (k_ >> 14) & 127, xx1 = (k_ >> 21) & 127;
                int r0 = y0 << 7, r1 = y1 << 7;
                float val = w.x * xc[r0 + xx0] + w.y * xc[r0 + xx1] +
                            w.z * xc[r1 + xx0] + w.w * xc[r1 + xx1];
                samp_s[c][p] = val;
                wt_s[c][p] = wtp[((kk * CIN + c0 + c) << 8) + o0 + p];
            }
            __syncthreads();
#pragma unroll
            for (int k = 0; k < 16; ++k) {
                float4 a  = *(const float4*)&wt_s[k][ty << 2];
                float4 bv = *(const float4*)&samp_s[k][tx << 2];
                acc[0][0] = fmaf(a.x, bv.x, acc[0][0]);
                acc[0][1] = fmaf(a.x, bv.y, acc[0][1]);
                acc[0][2] = fmaf(a.x, bv.z, acc[0][2]);
                acc[0][3] = fmaf(a.x, bv.w, acc[0][3]);
                acc[1][0] = fmaf(a.y, bv.x, acc[1][0]);
                acc[1][1] = fmaf(a.y, bv.y, acc[1][1]);
                acc[1][2] = fmaf(a.y, bv.z, acc[1][2]);
                acc[1][3] = fmaf(a.y, bv.w, acc[1][3]);
                acc[2][0] = fmaf(a.z, bv.x, acc[2][0]);
                acc[2][1] = fmaf(a.z, bv.y, acc[2][1]);
                acc[2][2] = fmaf(a.z, bv.z, acc[2][2]);
                acc[2][3] = fmaf(a.z, bv.w, acc[2][3]);
                acc[3][0] = fmaf(a.w, bv.x, acc[3][0]);
                acc[3][1] = fmaf(a.w, bv.y, acc[3][1]);
                acc[3][2] = fmaf(a.w, bv.z, acc[3][2]);
                acc[3][3] = fmaf(a.w, bv.w, acc[3][3]);
            }
            __syncthreads();
        }
    }

#pragma unroll
    for (int i = 0; i < 4; ++i) {
        int o = o0 + (ty << 2) + i;
        float4 r = make_float4(acc[i][0], acc[i][1], acc[i][2], acc[i][3]);
        *(float4*)&out[(((size_t)(b * COUT + o)) << 14) + pix0 + (tx << 2)] = r;
    }
}

// ---------------------------------------------------------------------------
extern "C" void kernel_launch(void* const* d_in, const int* in_sizes, int n_in,
                              void* d_out, int out_size, void* d_ws, size_t ws_size,
                              hipStream_t stream)
{
    const float* x    = (const float*)d_in[0];
    const float* offw = (const float*)d_in[1];
    const float* offb = (const float*)d_in[2];
    const float* modw = (const float*)d_in[3];
    const float* modb = (const float*)d_in[4];
    const float* wgt  = (const float*)d_in[5];
    float* out = (float*)d_out;

    char* wsb = (char*)d_ws;
    unsigned int* pk = (unsigned int*)wsb;                       // 2,359,296 B
    float4* w4 = (float4*)(wsb + 2359296);                       // 9,437,184 B
    float* wt  = (float*)(wsb + 2359296 + 9437184);              // 1,179,648 B

    // A: offset/mask conv + sampling tables
    offmask_kernel<<<dim3(WW / 32, HH / 16, NB), 256, 0, stream>>>(
        x, offw, offb, modw, modb, pk, w4);

    // C: weight transpose
    wtrans_kernel<<<dim3((COUT * CIN * 9) / 256), 256, 0, stream>>>(wgt, wt);

    // B: deformable GEMM
    dgemm_kernel<<<dim3(HWX / 64, COUT / 64, NB), 256, 0, stream>>>(
        x, wt, pk, w4, out);
}

// Round 2
// 572.338 us; speedup vs baseline: 2.5478x; 2.5478x over previous
//
#include <hip/hip_runtime.h>
#include <hip/hip_bf16.h>
#include <math.h>

#define CIN 128
#define HH 128
#define WW 128
#define HWX (HH*WW)
#define COUT 256
#define NB 4

typedef __attribute__((ext_vector_type(8))) short short8;
typedef __attribute__((ext_vector_type(4))) float f32x4;
typedef __attribute__((ext_vector_type(8))) unsigned short ushort8;

__device__ __forceinline__ unsigned short f2bf(float f) {
    union { float f; unsigned int u; } c; c.f = f;
    unsigned int u = c.u + 0x7FFF + ((c.u >> 16) & 1);   // RNE
    return (unsigned short)(u >> 16);
}

// ---------------------------------------------------------------------------
// Prep 1: pack offset/mod conv weights contiguously: wofft[c][t][28]
//   o<18 -> offw[o][c][t], o in 18..26 -> modw[o-18][c][t]
// ---------------------------------------------------------------------------
__global__ __launch_bounds__(256) void wpack_kernel(
    const float* __restrict__ offw, const float* __restrict__ modw,
    float* __restrict__ wofft)
{
    int i = blockIdx.x * 256 + threadIdx.x;
    if (i >= CIN * 9 * 28) return;
    int o = i % 28;
    int t = (i / 28) % 9;
    int c = i / 252;
    float v = 0.f;
    if (o < 18)      v = offw[(o * CIN + c) * 9 + t];
    else if (o < 27) v = modw[((o - 18) * CIN + c) * 9 + t];
    wofft[i] = v;
}

// ---------------------------------------------------------------------------
// Prep 2: bf16 A-fragment image for MFMA.
//   linear L = ((((kk*4+cc)*16 + mt)*64 + l)*8 + j)
//   o = mt*16 + (l&15);  c = cc*32 + (l>>4)*8 + j;  value = wgt[o][c][kk]
// ---------------------------------------------------------------------------
__global__ __launch_bounds__(256) void wimg_kernel(
    const float* __restrict__ wgt, unsigned short* __restrict__ wAi)
{
    int i = blockIdx.x * 256 + threadIdx.x;   // < 294912
    int j  = i & 7;
    int l  = (i >> 3) & 63;
    int mt = (i >> 9) & 15;
    int cc = (i >> 13) & 3;
    int kk = i >> 15;
    int o = mt * 16 + (l & 15);
    int c = cc * 32 + (l >> 4) * 8 + j;
    wAi[i] = f2bf(wgt[(o * CIN + c) * 9 + kk]);
}

// ---------------------------------------------------------------------------
// Kernel A: offset/mask conv + sampling-table epilogue.
// 32x8 px tile, 1 px/thread, weights via wave-uniform scalar loads.
// ---------------------------------------------------------------------------
__global__ __launch_bounds__(256) void offmask_kernel(
    const float* __restrict__ x, const float* __restrict__ wofft,
    const float* __restrict__ offb, const float* __restrict__ modb,
    unsigned int* __restrict__ pk_out, float4* __restrict__ w4_out)
{
    __shared__ float xs[8][10][34];

    const int tid = threadIdx.x;
    const int lx = tid & 31, ly = tid >> 5;
    const int b = blockIdx.z;
    const int ty0 = blockIdx.y * 8;
    const int tx0 = blockIdx.x * 32;
    const int ho = ty0 + ly, wo = tx0 + lx;

    float acc[27];
#pragma unroll
    for (int o = 0; o < 27; ++o) acc[o] = 0.f;

    for (int c0 = 0; c0 < CIN; c0 += 8) {
        for (int e = tid; e < 8 * 10 * 34; e += 256) {
            int c = e / 340;
            int rem = e - c * 340;
            int r = rem / 34;
            int col = rem - r * 34;
            int gy = ty0 + r - 1, gx = tx0 + col - 1;
            float v = 0.f;
            if (gy >= 0 && gy < HH && gx >= 0 && gx < WW)
                v = x[(((b * CIN) + (c0 + c)) << 14) + (gy << 7) + gx];
            xs[c][r][col] = v;
        }
        __syncthreads();

#pragma unroll 1
        for (int c = 0; c < 8; ++c) {
            float xv[3][3];
#pragma unroll
            for (int dy = 0; dy < 3; ++dy)
#pragma unroll
                for (int dx = 0; dx < 3; ++dx)
                    xv[dy][dx] = xs[c][ly + dy][lx + dx];
#pragma unroll
            for (int t = 0; t < 9; ++t) {
                const float* wp = wofft + ((c0 + c) * 9 + t) * 28;  // uniform -> s_load
                float xt = xv[t / 3][t % 3];
#pragma unroll
                for (int o = 0; o < 27; ++o)
                    acc[o] = fmaf(xt, wp[o], acc[o]);
            }
        }
        __syncthreads();
    }

    // epilogue: sampling tables (same math as verified round-1)
    const int pix = (ho << 7) + wo;
#pragma unroll
    for (int kk = 0; kk < 9; ++kk) {
        float oy = acc[2 * kk] + offb[2 * kk];
        float ox = acc[2 * kk + 1] + offb[2 * kk + 1];
        float mt = acc[18 + kk] + modb[kk];
        float m = 2.f / (1.f + expf(-mt));
        float py = (float)(ho - 1 + kk / 3) + oy;
        float px = (float)(wo - 1 + kk % 3) + ox;
        float y0f = floorf(py), x0f = floorf(px);
        float wy = py - y0f, wx = px - x0f;
        int y0 = (int)y0f, x0 = (int)x0f;
        int y1 = y0 + 1, x1 = x0 + 1;
        float vy0 = (y0 >= 0 && y0 < HH) ? 1.f : 0.f;
        float vy1 = (y1 >= 0 && y1 < HH) ? 1.f : 0.f;
        float vx0 = (x0 >= 0 && x0 < WW) ? 1.f : 0.f;
        float vx1 = (x1 >= 0 && x1 < WW) ? 1.f : 0.f;
        float a  = m * (1.f - wy) * vy0;
        float bb = m * wy * vy1;
        float u  = (1.f - wx) * vx0;
        float vv = wx * vx1;
        int y0c = min(max(y0, 0), HH - 1), y1c = min(max(y1, 0), HH - 1);
        int x0c = min(max(x0, 0), WW - 1), x1c = min(max(x1, 0), WW - 1);
        unsigned int pkv = (unsigned)y0c | ((unsigned)x0c << 7) |
                           ((unsigned)y1c << 14) | ((unsigned)x1c << 21);
        int oidx = ((b * 9 + kk) << 14) + pix;
        pk_out[oidx] = pkv;
        w4_out[oidx] = make_float4(a * u, a * vv, bb * u, bb * vv);
    }
}

// ---------------------------------------------------------------------------
// Kernel B: deformable GEMM via MFMA bf16.
// Block: M=256 (full Cout) x N=64 px; 4 waves, wave w -> o in [w*64, w*64+64).
// K-chunks of 32 channels within each kk. Fragment-direct LDS layouts:
//   ldsA[tile(16)][lane(64)][8 bf16], ldsB[ntile(4)][lane(64)][8 bf16]
// so every frag access is a conflict-free ds_read/ds_write_b128 at lane*16.
// ---------------------------------------------------------------------------
__global__ __launch_bounds__(256) void dgemm_kernel(
    const float* __restrict__ x, const unsigned short* __restrict__ wAi,
    const unsigned int* __restrict__ pk, const float4* __restrict__ w4,
    float* __restrict__ out)
{
    __shared__ unsigned short ldsA[16 * 64 * 8];   // 16 KB
    __shared__ unsigned short ldsB[4 * 64 * 8];    // 4 KB

    const int tid  = threadIdx.x;
    const int l    = tid & 63;
    const int wave = tid >> 6;
    const int pix0 = blockIdx.x * 64;
    const int b    = blockIdx.z;

    // gather-role mapping: thread owns fragline f = tid
    const int g_ntile = tid >> 6;
    const int g_n     = l & 15;
    const int g_q     = l >> 4;            // k-octet within 32-chunk
    const int g_px    = pix0 + g_ntile * 16 + g_n;

    f32x4 acc[4][4];
#pragma unroll
    for (int i = 0; i < 4; ++i)
#pragma unroll
        for (int j = 0; j < 4; ++j)
            acc[i][j] = (f32x4){0.f, 0.f, 0.f, 0.f};

    for (int kk = 0; kk < 9; ++kk) {
        // per-thread sampling descriptor for its pixel
        int gi = ((b * 9 + kk) << 14) + g_px;
        unsigned int pkv = pk[gi];
        float4 wv = w4[gi];
        int y0 = pkv & 127, x0c = (pkv >> 7) & 127;
        int y1 = (pkv >> 14) & 127, x1c = (pkv >> 21) & 127;
        int o00 = (y0 << 7) + x0c, o01 = (y0 << 7) + x1c;
        int o10 = (y1 << 7) + x0c, o11 = (y1 << 7) + x1c;

        for (int cc = 0; cc < 4; ++cc) {
            __syncthreads();   // previous chunk's frag reads complete

            // stage A image chunk: 16 KB, coalesced float4 copies
            {
                const float4* src = (const float4*)(wAi + ((kk * 4 + cc) << 13));
                float4* dst = (float4*)ldsA;
                dst[tid * 4 + 0] = src[tid * 4 + 0];
                dst[tid * 4 + 1] = src[tid * 4 + 1];
                dst[tid * 4 + 2] = src[tid * 4 + 2];
                dst[tid * 4 + 3] = src[tid * 4 + 3];
            }

            // gather 8 bilinear samples (channels c_base..c_base+7) for g_px
            {
                const float* p = x + (((size_t)(b * CIN + cc * 32 + g_q * 8)) << 14);
                unsigned short v[8];
#pragma unroll
                for (int j = 0; j < 8; ++j) {
                    float val = wv.x * p[o00] + wv.y * p[o01] +
                                wv.z * p[o10] + wv.w * p[o11];
                    v[j] = f2bf(val);
                    p += HWX;
                }
                ushort8 pkd = {v[0], v[1], v[2], v[3], v[4], v[5], v[6], v[7]};
                *(ushort8*)&ldsB[tid * 8] = pkd;
            }

            __syncthreads();

            short8 afr[4], bfr[4];
#pragma unroll
            for (int mt = 0; mt < 4; ++mt)
                afr[mt] = *(short8*)&ldsA[((wave * 4 + mt) * 64 + l) * 8];
#pragma unroll
            for (int nt = 0; nt < 4; ++nt)
                bfr[nt] = *(short8*)&ldsB[(nt * 64 + l) * 8];
#pragma unroll
            for (int mt = 0; mt < 4; ++mt)
#pragma unroll
                for (int nt = 0; nt < 4; ++nt)
                    acc[mt][nt] = __builtin_amdgcn_mfma_f32_16x16x32_bf16(
                        afr[mt], bfr[nt], acc[mt][nt], 0, 0, 0);
        }
    }

    // epilogue: C/D layout col=lane&15, row=(lane>>4)*4+reg
    const int ccol = l & 15;
    const int crow = (l >> 4) * 4;
#pragma unroll
    for (int mt = 0; mt < 4; ++mt) {
#pragma unroll
        for (int nt = 0; nt < 4; ++nt) {
            int px = pix0 + nt * 16 + ccol;
#pragma unroll
            for (int r = 0; r < 4; ++r) {
                int o = wave * 64 + mt * 16 + crow + r;
                out[(((size_t)(b * COUT + o)) << 14) + px] = acc[mt][nt][r];
            }
        }
    }
}

// ---------------------------------------------------------------------------
extern "C" void kernel_launch(void* const* d_in, const int* in_sizes, int n_in,
                              void* d_out, int out_size, void* d_ws, size_t ws_size,
                              hipStream_t stream)
{
    const float* x    = (const float*)d_in[0];
    const float* offw = (const float*)d_in[1];
    const float* offb = (const float*)d_in[2];
    const float* modw = (const float*)d_in[3];
    const float* modb = (const float*)d_in[4];
    const float* wgt  = (const float*)d_in[5];
    float* out = (float*)d_out;

    char* wsb = (char*)d_ws;
    unsigned int*   pkp   = (unsigned int*)wsb;                         // 2,359,296 B
    float4*         w4p   = (float4*)(wsb + 2359296);                   // 9,437,184 B
    unsigned short* wAi   = (unsigned short*)(wsb + 11796480);          //   589,824 B
    float*          wofft = (float*)(wsb + 12386304);                   //   129,024 B

    wpack_kernel<<<dim3((CIN * 9 * 28 + 255) / 256), 256, 0, stream>>>(offw, modw, wofft);
    wimg_kernel<<<dim3(COUT * CIN * 9 / 256), 256, 0, stream>>>(wgt, wAi);
    offmask_kernel<<<dim3(WW / 32, HH / 8, NB), 256, 0, stream>>>(
        x, wofft, offb, modb, pkp, w4p);
    dgemm_kernel<<<dim3(HWX / 64, 1, NB), 256, 0, stream>>>(x, wAi, pkp, w4p, out);
}

// Round 3
// 418.838 us; speedup vs baseline: 3.4816x; 1.3665x over previous
//
#include <hip/hip_runtime.h>
#include <hip/hip_bf16.h>
#include <math.h>

#define CIN 128
#define HH 128
#define WW 128
#define HWX (HH*WW)
#define COUT 256
#define NB 4

typedef __attribute__((ext_vector_type(8))) short short8;
typedef __attribute__((ext_vector_type(4))) float f32x4;
typedef __attribute__((ext_vector_type(8))) unsigned short ushort8;

__device__ __forceinline__ unsigned short f2bf(float f) {
    union { float f; unsigned int u; } c; c.f = f;
    unsigned int u = c.u + 0x7FFF + ((c.u >> 16) & 1);   // RNE
    return (unsigned short)(u >> 16);
}
__device__ __forceinline__ float bf2f(unsigned short u) {
    union { unsigned int u; float f; } c; c.u = ((unsigned int)u) << 16;
    return c.f;
}

// ---------------------------------------------------------------------------
// Prep 1: pack offset/mod conv weights contiguously: wofft[c][t][28]
// ---------------------------------------------------------------------------
__global__ __launch_bounds__(256) void wpack_kernel(
    const float* __restrict__ offw, const float* __restrict__ modw,
    float* __restrict__ wofft)
{
    int i = blockIdx.x * 256 + threadIdx.x;
    if (i >= CIN * 9 * 28) return;
    int o = i % 28;
    int t = (i / 28) % 9;
    int c = i / 252;
    float v = 0.f;
    if (o < 18)      v = offw[(o * CIN + c) * 9 + t];
    else if (o < 27) v = modw[((o - 18) * CIN + c) * 9 + t];
    wofft[i] = v;
}

// ---------------------------------------------------------------------------
// Prep 2: bf16 A-fragment image for MFMA (verified in round 2).
//   L = ((((kk*4+cc)*16 + mt)*64 + l)*8 + j)
//   o = mt*16 + (l&15);  c = cc*32 + (l>>4)*8 + j;  value = wgt[o][c][kk]
// ---------------------------------------------------------------------------
__global__ __launch_bounds__(256) void wimg_kernel(
    const float* __restrict__ wgt, unsigned short* __restrict__ wAi)
{
    int i = blockIdx.x * 256 + threadIdx.x;   // < 294912
    int j  = i & 7;
    int l  = (i >> 3) & 63;
    int mt = (i >> 9) & 15;
    int cc = (i >> 13) & 3;
    int kk = i >> 15;
    int o = mt * 16 + (l & 15);
    int c = cc * 32 + (l >> 4) * 8 + j;
    wAi[i] = f2bf(wgt[(o * CIN + c) * 9 + kk]);
}

// ---------------------------------------------------------------------------
// Kernel A1: partial offset/mask conv over a 32-channel chunk.
// 32x8 px tile, 1 px/thread; grid z = b*4 + chunk -> 1024 blocks (4 w/SIMD).
// Writes bf16 partials part[(b*4+chunk)*27 + o][pix].
// ---------------------------------------------------------------------------
__global__ __launch_bounds__(256) void convpart_kernel(
    const float* __restrict__ x, const float* __restrict__ wofft,
    unsigned short* __restrict__ part)
{
    __shared__ float xs[8][10][34];

    const int tid = threadIdx.x;
    const int lx = tid & 31, ly = tid >> 5;
    const int z = blockIdx.z;               // b*4 + chunk
    const int b = z >> 2, chunk = z & 3;
    const int cbase = chunk * 32;
    const int ty0 = blockIdx.y * 8;
    const int tx0 = blockIdx.x * 32;
    const int ho = ty0 + ly, wo = tx0 + lx;

    float acc[27];
#pragma unroll
    for (int o = 0; o < 27; ++o) acc[o] = 0.f;

    for (int c0 = 0; c0 < 32; c0 += 8) {
        for (int e = tid; e < 8 * 10 * 34; e += 256) {
            int c = e / 340;
            int rem = e - c * 340;
            int r = rem / 34;
            int col = rem - r * 34;
            int gy = ty0 + r - 1, gx = tx0 + col - 1;
            float v = 0.f;
            if (gy >= 0 && gy < HH && gx >= 0 && gx < WW)
                v = x[(((b * CIN) + (cbase + c0 + c)) << 14) + (gy << 7) + gx];
            xs[c][r][col] = v;
        }
        __syncthreads();

#pragma unroll 1
        for (int c = 0; c < 8; ++c) {
            float xv[3][3];
#pragma unroll
            for (int dy = 0; dy < 3; ++dy)
#pragma unroll
                for (int dx = 0; dx < 3; ++dx)
                    xv[dy][dx] = xs[c][ly + dy][lx + dx];
#pragma unroll
            for (int t = 0; t < 9; ++t) {
                const float* wp = wofft + ((cbase + c0 + c) * 9 + t) * 28;
                float xt = xv[t / 3][t % 3];
#pragma unroll
                for (int o = 0; o < 27; ++o)
                    acc[o] = fmaf(xt, wp[o], acc[o]);
            }
        }
        __syncthreads();
    }

    const int pix = (ho << 7) + wo;
    unsigned short* pp = part + (((z * 27) << 14)) + pix;
#pragma unroll
    for (int o = 0; o < 27; ++o)
        pp[o << 14] = f2bf(acc[o]);
}

// ---------------------------------------------------------------------------
// Kernel A2: combine partials + sampling-table epilogue.
// 1 thread per (b, kk, pix): gid = ((b*9+kk)<<14) + pix.
// ---------------------------------------------------------------------------
__global__ __launch_bounds__(256) void tables_kernel(
    const unsigned short* __restrict__ part, const float* __restrict__ offb,
    const float* __restrict__ modb,
    unsigned int* __restrict__ pk_out, float4* __restrict__ w4_out)
{
    const int gid = blockIdx.x * 256 + threadIdx.x;
    const int pix = gid & 16383;
    const int t = gid >> 14;                // b*9 + kk
    const int kk = t % 9;
    const int b = t / 9;
    const int ho = pix >> 7, wo = pix & 127;

    float oy = 0.f, ox = 0.f, mt = 0.f;
#pragma unroll
    for (int ch = 0; ch < 4; ++ch) {
        const unsigned short* pp = part + ((((b * 4 + ch) * 27) << 14)) + pix;
        oy += bf2f(pp[(2 * kk) << 14]);
        ox += bf2f(pp[(2 * kk + 1) << 14]);
        mt += bf2f(pp[(18 + kk) << 14]);
    }
    oy += offb[2 * kk];
    ox += offb[2 * kk + 1];
    mt += modb[kk];

    float m = 2.f / (1.f + expf(-mt));
    float py = (float)(ho - 1 + kk / 3) + oy;
    float px = (float)(wo - 1 + kk % 3) + ox;
    float y0f = floorf(py), x0f = floorf(px);
    float wy = py - y0f, wx = px - x0f;
    int y0 = (int)y0f, x0 = (int)x0f;
    int y1 = y0 + 1, x1 = x0 + 1;
    float vy0 = (y0 >= 0 && y0 < HH) ? 1.f : 0.f;
    float vy1 = (y1 >= 0 && y1 < HH) ? 1.f : 0.f;
    float vx0 = (x0 >= 0 && x0 < WW) ? 1.f : 0.f;
    float vx1 = (x1 >= 0 && x1 < WW) ? 1.f : 0.f;
    float a  = m * (1.f - wy) * vy0;
    float bb = m * wy * vy1;
    float u  = (1.f - wx) * vx0;
    float vv = wx * vx1;
    int y0c = min(max(y0, 0), HH - 1), y1c = min(max(y1, 0), HH - 1);
    int x0c = min(max(x0, 0), WW - 1), x1c = min(max(x1, 0), WW - 1);
    unsigned int pkv = (unsigned)y0c | ((unsigned)x0c << 7) |
                       ((unsigned)y1c << 14) | ((unsigned)x1c << 21);
    pk_out[gid] = pkv;
    w4_out[gid] = make_float4(a * u, a * vv, bb * u, bb * vv);
}

// ---------------------------------------------------------------------------
// Kernel B: barrier-free deformable GEMM via MFMA bf16.
// Block = 64 px x full Cout=256. Wave w owns N-tile w (16 px) and all 16
// M-tiles. B fragments gathered directly into registers (lane l: pixel
// pix0+w*16+(l&15), k-octet l>>4). A fragments loaded coalesced from the
// global fragment image (L2-hot). No LDS, no __syncthreads.
// ---------------------------------------------------------------------------
__global__ __launch_bounds__(256, 4) void dgemm_kernel(
    const float* __restrict__ x, const unsigned short* __restrict__ wAi,
    const unsigned int* __restrict__ pk, const float4* __restrict__ w4,
    float* __restrict__ out)
{
    const int tid  = threadIdx.x;
    const int l    = tid & 63;
    const int wave = tid >> 6;
    const int pix0 = blockIdx.x * 64;
    const int b    = blockIdx.z;
    const int q    = l >> 4;                    // k-octet
    const int px   = pix0 + wave * 16 + (l & 15);

    f32x4 acc[16];
#pragma unroll
    for (int i = 0; i < 16; ++i) acc[i] = (f32x4){0.f, 0.f, 0.f, 0.f};

    for (int kk = 0; kk < 9; ++kk) {
        int gi = ((b * 9 + kk) << 14) + px;
        unsigned int pkv = pk[gi];
        float4 wv = w4[gi];
        int y0 = pkv & 127, x0c = (pkv >> 7) & 127;
        int y1 = (pkv >> 14) & 127, x1c = (pkv >> 21) & 127;
        int o00 = (y0 << 7) + x0c, o01 = (y0 << 7) + x1c;
        int o10 = (y1 << 7) + x0c, o11 = (y1 << 7) + x1c;

#pragma unroll 1
        for (int cc = 0; cc < 4; ++cc) {
            // gather B fragment: 8 channels (octet q) for this pixel
            const float* p = x + (((size_t)(b * CIN + cc * 32 + q * 8)) << 14);
            unsigned short v[8];
#pragma unroll
            for (int j = 0; j < 8; ++j) {
                float val = wv.x * p[o00] + wv.y * p[o01] +
                            wv.z * p[o10] + wv.w * p[o11];
                v[j] = f2bf(val);
                p += HWX;
            }
            ushort8 pkd = {v[0], v[1], v[2], v[3], v[4], v[5], v[6], v[7]};
            short8 bfr = *(short8*)&pkd;

            // A fragments from global (coalesced dwordx4, L2-hot), 2 groups
            const short8* ab = (const short8*)(wAi + (((kk << 2) + cc) << 13)) + l;
#pragma unroll
            for (int g = 0; g < 2; ++g) {
                short8 af[8];
#pragma unroll
                for (int m = 0; m < 8; ++m) af[m] = ab[(g * 8 + m) * 64];
#pragma unroll
                for (int m = 0; m < 8; ++m)
                    acc[g * 8 + m] = __builtin_amdgcn_mfma_f32_16x16x32_bf16(
                        af[m], bfr, acc[g * 8 + m], 0, 0, 0);
            }
        }
    }

    // epilogue: C/D layout col=lane&15 (=px), row=(lane>>4)*4+reg
    const int crow = q * 4;
#pragma unroll
    for (int mt = 0; mt < 16; ++mt) {
#pragma unroll
        for (int r = 0; r < 4; ++r) {
            int o = mt * 16 + crow + r;
            out[(((size_t)(b * COUT + o)) << 14) + px] = acc[mt][r];
        }
    }
}

// ---------------------------------------------------------------------------
extern "C" void kernel_launch(void* const* d_in, const int* in_sizes, int n_in,
                              void* d_out, int out_size, void* d_ws, size_t ws_size,
                              hipStream_t stream)
{
    const float* x    = (const float*)d_in[0];
    const float* offw = (const float*)d_in[1];
    const float* offb = (const float*)d_in[2];
    const float* modw = (const float*)d_in[3];
    const float* modb = (const float*)d_in[4];
    const float* wgt  = (const float*)d_in[5];
    float* out = (float*)d_out;

    char* wsb = (char*)d_ws;
    unsigned int*   pkp   = (unsigned int*)wsb;                    //  2,359,296 B
    float4*         w4p   = (float4*)(wsb + 2359296);              //  9,437,184 B
    unsigned short* wAi   = (unsigned short*)(wsb + 11796480);     //    589,824 B
    float*          wofft = (float*)(wsb + 12386304);              //    129,024 B
    unsigned short* part  = (unsigned short*)(wsb + 12515328);     // 14,155,776 B
    // total ws use: 26,671,104 B

    wpack_kernel<<<dim3((CIN * 9 * 28 + 255) / 256), 256, 0, stream>>>(offw, modw, wofft);
    wimg_kernel<<<dim3(COUT * CIN * 9 / 256), 256, 0, stream>>>(wgt, wAi);
    convpart_kernel<<<dim3(WW / 32, HH / 8, NB * 4), 256, 0, stream>>>(x, wofft, part);
    tables_kernel<<<dim3(NB * 9 * HWX / 256), 256, 0, stream>>>(part, offb, modb, pkp, w4p);
    dgemm_kernel<<<dim3(HWX / 64, 1, NB), 256, 0, stream>>>(x, wAi, pkp, w4p, out);
}